// Round 3
// baseline (69.883 us; speedup 1.0000x reference)
//
#include <hip/hip_runtime.h>

// Problem constants (from reference): B=8192, N=34, D=16
#define BB 8192
#define NN 34
#define DD 16
#define PP 594   // #pairs: i in [0,32], j in [i,33]

typedef float f32x4 __attribute__((ext_vector_type(4)));

// Compile-time pair table: p -> {i, j}
struct PairTab { uchar2 v[PP]; };
constexpr PairTab make_tab() {
    PairTab t{};
    int p = 0;
    for (int i = 0; i < NN - 1; ++i)
        for (int j = i; j < NN; ++j) {
            t.v[p].x = (unsigned char)i;
            t.v[p].y = (unsigned char)j;
            ++p;
        }
    return t;
}
__device__ __constant__ PairTab c_tab = make_tab();

__global__ __launch_bounds__(256)
void BiInteraction_38577396253196_kernel(const float* __restrict__ x,
                                         const float* __restrict__ W,
                                         float* __restrict__ out)
{
    __shared__ float xs[NN * DD];   // 544 floats: x[b]
    __shared__ float ws[DD * DD];   // 256 floats: W
    __shared__ float ps[NN * DD];   // 544 floats: proj[b] = x[b] @ W

    const int b = blockIdx.x;
    const int t = threadIdx.x;

    // Stage x[b] (136 float4, streamed once -> nontemporal) and W (64 float4,
    // hot across all blocks -> cached) into LDS.
    const f32x4* xg = (const f32x4*)(x + (size_t)b * (NN * DD));
    if (t < 136) ((f32x4*)xs)[t] = __builtin_nontemporal_load(&xg[t]);
    if (t >= 192) ((f32x4*)ws)[t - 192] = ((const f32x4*)W)[t - 192];
    __syncthreads();

    // proj[n][e] = sum_d x[n][d] * W[d][e]   (544 outputs, 16 FMAs each)
    for (int q = t; q < NN * DD; q += 256) {
        const int n = q >> 4, e = q & 15;
        float acc = 0.f;
#pragma unroll
        for (int d = 0; d < DD; ++d)
            acc = fmaf(xs[n * DD + d], ws[d * DD + e], acc);
        ps[q] = acc;
    }
    __syncthreads();

    // out[b, p*16 + d] = proj[i[p]][d] * x[j[p]][d].
    // Flat float4 index k4 strided by thread -> coalesced 16B/lane stores.
    // PP*4 = 2376 = 9*256 + 72: 9 unrolled full iterations + masked tail.
    // Nontemporal: pure streaming write, no L2/L3 allocation.
    f32x4* og = (f32x4*)(out + (size_t)b * (PP * DD));
    const f32x4* psv = (const f32x4*)ps;
    const f32x4* xsv = (const f32x4*)xs;
#pragma unroll
    for (int it = 0; it < 9; ++it) {
        const int k4 = t + it * 256;
        const int p = k4 >> 2, d4 = k4 & 3;
        const uchar2 pr = c_tab.v[p];
        const f32x4 r = psv[pr.x * 4 + d4] * xsv[pr.y * 4 + d4];
        __builtin_nontemporal_store(r, &og[k4]);
    }
    if (t < 72) {
        const int k4 = t + 9 * 256;
        const int p = k4 >> 2, d4 = k4 & 3;
        const uchar2 pr = c_tab.v[p];
        const f32x4 r = psv[pr.x * 4 + d4] * xsv[pr.y * 4 + d4];
        __builtin_nontemporal_store(r, &og[k4]);
    }
}

extern "C" void kernel_launch(void* const* d_in, const int* in_sizes, int n_in,
                              void* d_out, int out_size, void* d_ws, size_t ws_size,
                              hipStream_t stream) {
    const float* x = (const float*)d_in[0];   // [B, N, D] fp32
    const float* W = (const float*)d_in[1];   // [D, D] fp32
    float* out = (float*)d_out;               // [B, P*D] fp32

    BiInteraction_38577396253196_kernel<<<BB, 256, 0, stream>>>(x, W, out);
}

// Round 4
// 68.293 us; speedup vs baseline: 1.0233x; 1.0233x over previous
//
#include <hip/hip_runtime.h>

// Problem constants (from reference): B=8192, N=34, D=16
#define BB 8192
#define NN 34
#define DD 16
#define PP 594        // #pairs: i in [0,32], j in [i,33]
#define XF 544        // NN*DD floats per batch
#define NBATCH 4      // batches per block: one per wave, wave-private LDS

typedef float f32x4 __attribute__((ext_vector_type(4)));

// Compile-time pair table: p -> {i, j}
struct PairTab { uchar2 v[PP]; };
constexpr PairTab make_tab() {
    PairTab t{};
    int p = 0;
    for (int i = 0; i < NN - 1; ++i)
        for (int j = i; j < NN; ++j) {
            t.v[p].x = (unsigned char)i;
            t.v[p].y = (unsigned char)j;
            ++p;
        }
    return t;
}
__device__ __constant__ PairTab c_tab = make_tab();

__global__ __launch_bounds__(256)
void BiInteraction_38577396253196_kernel(const float* __restrict__ x,
                                         const float* __restrict__ W,
                                         float* __restrict__ out)
{
    // Per-wave private LDS: 544 xs + 544 ps + 256 ws floats = 5.25 KiB/wave.
    __shared__ float sh[NBATCH * (XF + XF + DD * DD)];

    const int t = threadIdx.x;
    const int w = t >> 6, lane = t & 63;
    const int b = blockIdx.x * NBATCH + w;   // this wave's batch

    float* xs = sh + w * (XF + XF + DD * DD);
    float* ps = xs + XF;
    float* ws = ps + XF;

    // Stage x[b] (136 float4) and W (64 float4) into this wave's LDS.
    const f32x4* xg = (const f32x4*)(x + (size_t)b * XF);
    f32x4* xsv = (f32x4*)xs;
    xsv[lane]      = xg[lane];
    xsv[lane + 64] = xg[lane + 64];
    if (lane < 8) xsv[lane + 128] = xg[lane + 128];
    ((f32x4*)ws)[lane] = ((const f32x4*)W)[lane];

    // Wave-private data: no __syncthreads needed; wave_barrier pins ordering
    // (zero-cost compiler fence; lgkmcnt waits are compiler-inserted).
    __builtin_amdgcn_wave_barrier();

    // proj[n][e] = sum_d x[n][d] * W[d][e]  (544 outputs, 16 FMAs each)
#pragma unroll
    for (int it = 0; it < 8; ++it) {
        const int q = lane + it * 64;
        const int n = q >> 4, e = q & 15;
        float acc = 0.f;
#pragma unroll
        for (int d = 0; d < DD; ++d)
            acc = fmaf(xs[n * DD + d], ws[d * DD + e], acc);
        ps[q] = acc;
    }
    if (lane < 32) {
        const int q = lane + 512;
        const int n = q >> 4, e = q & 15;
        float acc = 0.f;
#pragma unroll
        for (int d = 0; d < DD; ++d)
            acc = fmaf(xs[n * DD + d], ws[d * DD + e], acc);
        ps[q] = acc;
    }

    __builtin_amdgcn_wave_barrier();

    // out[b, p*16+d] = proj[i[p]][d] * x[j[p]][d]; flat float4 index strided
    // by lane -> coalesced 1 KiB/wave stores. 2376 = 37*64 + 8.
    f32x4* og = (f32x4*)(out + (size_t)b * (PP * DD));
    const f32x4* psv = (const f32x4*)ps;
#pragma unroll 8
    for (int it = 0; it < 37; ++it) {
        const int k4 = lane + it * 64;
        const int p = k4 >> 2, d4 = k4 & 3;
        const uchar2 pr = c_tab.v[p];
        og[k4] = psv[pr.x * 4 + d4] * xsv[pr.y * 4 + d4];
    }
    if (lane < 8) {
        const int k4 = lane + 37 * 64;
        const int p = k4 >> 2, d4 = k4 & 3;
        const uchar2 pr = c_tab.v[p];
        og[k4] = psv[pr.x * 4 + d4] * xsv[pr.y * 4 + d4];
    }
}

extern "C" void kernel_launch(void* const* d_in, const int* in_sizes, int n_in,
                              void* d_out, int out_size, void* d_ws, size_t ws_size,
                              hipStream_t stream) {
    const float* x = (const float*)d_in[0];   // [B, N, D] fp32
    const float* W = (const float*)d_in[1];   // [D, D] fp32
    float* out = (float*)d_out;               // [B, P*D] fp32

    BiInteraction_38577396253196_kernel<<<BB / NBATCH, 256, 0, stream>>>(x, W, out);
}

// Round 5
// 65.660 us; speedup vs baseline: 1.0643x; 1.0401x over previous
//
#include <hip/hip_runtime.h>

// Problem constants (from reference): B=8192, N=34, D=16
#define BB 8192
#define NN 34
#define DD 16
#define PP 594        // #pairs: i in [0,32], j in [i,33]
#define XF 544        // NN*DD floats per batch
#define NB 4          // consecutive batches per block (x/out contiguous across them)

typedef float f32x4 __attribute__((ext_vector_type(4)));

// Compile-time pair table: p -> {i, j}
struct PairTab { uchar2 v[PP]; };
constexpr PairTab make_tab() {
    PairTab t{};
    int p = 0;
    for (int i = 0; i < NN - 1; ++i)
        for (int j = i; j < NN; ++j) {
            t.v[p].x = (unsigned char)i;
            t.v[p].y = (unsigned char)j;
            ++p;
        }
    return t;
}
__device__ __constant__ PairTab c_tab = make_tab();

__global__ __launch_bounds__(256)
void BiInteraction_38577396253196_kernel(const float* __restrict__ x,
                                         const float* __restrict__ W,
                                         float* __restrict__ out)
{
    __shared__ float xs[NB * XF];    // 2176 floats: x for 4 consecutive batches
    __shared__ float ps[NB * XF];    // 2176 floats: proj for 4 batches
    __shared__ float ws[DD * DD];    // 256 floats: W

    const int t = threadIdx.x;
    const size_t b0 = (size_t)blockIdx.x * NB;

    // Stage x[b0..b0+3] (contiguous: 544 float4) and W (64 float4).
    const f32x4* xg = (const f32x4*)(x + b0 * XF);
    f32x4* xsv = (f32x4*)xs;
    xsv[t]       = xg[t];
    xsv[t + 256] = xg[t + 256];
    if (t < 32) xsv[t + 512] = xg[t + 512];
    if (t < 64) ((f32x4*)ws)[t] = ((const f32x4*)W)[t];
    __syncthreads();

    // proj[n][e] = sum_d x[n][d] * W[d][e]; n in [0,136) spans the 4 batches
    // (back-to-back layout makes this one flat loop). 2176 = 8*256 + 128.
#pragma unroll
    for (int it = 0; it < 8; ++it) {
        const int q = t + it * 256;
        const int n = q >> 4, e = q & 15;
        float acc = 0.f;
#pragma unroll
        for (int d = 0; d < DD; ++d)
            acc = fmaf(xs[n * DD + d], ws[d * DD + e], acc);
        ps[q] = acc;
    }
    if (t < 128) {
        const int q = t + 2048;
        const int n = q >> 4, e = q & 15;
        float acc = 0.f;
#pragma unroll
        for (int d = 0; d < DD; ++d)
            acc = fmaf(xs[n * DD + d], ws[d * DD + e], acc);
        ps[q] = acc;
    }
    __syncthreads();

    // Stores: per batch, flat float4 index k4 strided by thread -> coalesced
    // 1 KiB/wave stores; 2376 = 9*256 + 72. Full unroll over batches lets the
    // compiler CSE the c_tab gathers (same k4 -> same pair) across all 4.
#pragma unroll
    for (int w4 = 0; w4 < NB; ++w4) {
        f32x4* og = (f32x4*)(out + (b0 + w4) * (size_t)(PP * DD));
        const f32x4* psv = (const f32x4*)(ps + w4 * XF);
        const f32x4* xv  = (const f32x4*)(xs + w4 * XF);
#pragma unroll
        for (int it = 0; it < 9; ++it) {
            const int k4 = t + it * 256;
            const int p = k4 >> 2, d4 = k4 & 3;
            const uchar2 pr = c_tab.v[p];
            og[k4] = psv[pr.x * 4 + d4] * xv[pr.y * 4 + d4];
        }
        if (t < 72) {
            const int k4 = t + 9 * 256;
            const int p = k4 >> 2, d4 = k4 & 3;
            const uchar2 pr = c_tab.v[p];
            og[k4] = psv[pr.x * 4 + d4] * xv[pr.y * 4 + d4];
        }
    }
}

extern "C" void kernel_launch(void* const* d_in, const int* in_sizes, int n_in,
                              void* d_out, int out_size, void* d_ws, size_t ws_size,
                              hipStream_t stream) {
    const float* x = (const float*)d_in[0];   // [B, N, D] fp32
    const float* W = (const float*)d_in[1];   // [D, D] fp32
    float* out = (float*)d_out;               // [B, P*D] fp32

    BiInteraction_38577396253196_kernel<<<BB / NB, 256, 0, stream>>>(x, W, out);
}